// Round 14
// baseline (197.752 us; speedup 1.0000x reference)
//
#include <hip/hip_runtime.h>
#include <hip/hip_bf16.h>

#define NN 50000
#define NE 500000
#define HD 128
#define CAP 48
#define PREP_B 24
#define ZCUR_B ((NN + 255) / 256)          // 196
#define ZAGGR_B 6250
#define XCONV_B 3125
#define K1_B (PREP_B + ZCUR_B + ZAGGR_B + XCONV_B)   // 9595
#define FILLB_B ((NE + 255) / 256)         // 1954

typedef __bf16 bf16;
typedef __attribute__((ext_vector_type(8))) __bf16 bf16x8;
typedef __attribute__((ext_vector_type(4))) float floatx4;

__device__ inline float u2f(unsigned int lo16) {
    union { unsigned int i; float f; } c; c.i = lo16 << 16; return c.f;
}

__device__ inline bf16x8 cvt8(floatx4 a, floatx4 b) {
    bf16x8 r;
#pragma unroll
    for (int j = 0; j < 4; j++) { r[j] = (bf16)a[j]; r[j + 4] = (bf16)b[j]; }
    return r;
}

__device__ inline void split8(const floatx4 f0, const floatx4 f1, bf16x8& hi, bf16x8& lo) {
#pragma unroll
    for (int j = 0; j < 4; j++) {
        float a = f0[j]; bf16 h = (bf16)a; hi[j] = h; lo[j] = (bf16)(a - (float)h);
        float b = f1[j]; bf16 g = (bf16)b; hi[j + 4] = g; lo[j + 4] = (bf16)(b - (float)g);
    }
}

__device__ inline bf16x8 zero8() {
    bf16x8 v;
#pragma unroll
    for (int j = 0; j < 8; j++) v[j] = (bf16)0.f;
    return v;
}

// ===== K1: weights->bf16 (24) | zero cur (196) | zero aggr (6250) | x->bf16 (3125) =====
__global__ __launch_bounds__(256) void k_setup1(
    const float* __restrict__ wl, const float* __restrict__ w0, const float* __restrict__ w1,
    const float* __restrict__ bl, const float* __restrict__ b0, const float* __restrict__ b1,
    const float* __restrict__ ow, const float* __restrict__ ob,
    const float* __restrict__ x,
    bf16* __restrict__ wlb, bf16* __restrict__ w01b, bf16* __restrict__ owb,
    float* __restrict__ bias1, float* __restrict__ bias2,
    float* __restrict__ aggr, int* __restrict__ cur, bf16* __restrict__ xb, int tier)
{
    const int b = blockIdx.x, tid = threadIdx.x;
    if (b < PREP_B) {
        int g = b * 256 + tid;
        int m = g >> 11, off = (g & 2047) << 3;
        if (m == 0) {
            const floatx4 a = *(const floatx4*)(wl + off);
            const floatx4 c = *(const floatx4*)(wl + off + 4);
            *(bf16x8*)(wlb + off) = cvt8(a, c);
        } else if (m == 1) {
            floatx4 a = *(const floatx4*)(w0 + off);
            floatx4 c = *(const floatx4*)(w0 + off + 4);
            const floatx4 d = *(const floatx4*)(w1 + off);
            const floatx4 e = *(const floatx4*)(w1 + off + 4);
#pragma unroll
            for (int j = 0; j < 4; j++) { a[j] += d[j]; c[j] += e[j]; }
            *(bf16x8*)(w01b + off) = cvt8(a, c);
        } else {
            const floatx4 a = *(const floatx4*)(ow + off);
            const floatx4 c = *(const floatx4*)(ow + off + 4);
            *(bf16x8*)(owb + off) = cvt8(a, c);
        }
        if (g < 128) bias1[g] = bl[g] + b0[g] + b1[g];
        else if (g < 256) bias2[g - 128] = ob[g - 128];
    } else if (b < PREP_B + ZCUR_B) {
        if (tier >= 1) {
            int i = (b - PREP_B) * 256 + tid;
            if (i < NN) cur[i] = 0;
        }
    } else if (b < PREP_B + ZCUR_B + ZAGGR_B) {
        int i = (b - PREP_B - ZCUR_B) * 256 + tid;
        floatx4 z = {0.f, 0.f, 0.f, 0.f};
        ((floatx4*)aggr)[i] = z;
    } else {
        if (tier >= 1) {
            int off = ((b - PREP_B - ZCUR_B - ZAGGR_B) * 256 + tid) << 3;
            const floatx4 a = *(const floatx4*)(x + off);
            const floatx4 c = *(const floatx4*)(x + off + 4);
            *(bf16x8*)(xb + off) = cvt8(a, c);
        }
    }
}

// ===== bucket append only (clean dispatch): bucket[dst*CAP+pos]=src; overflow valve =====
__global__ __launch_bounds__(256) void k_fillb(const int* __restrict__ edge,
                                               const float* __restrict__ x,
                                               int* __restrict__ cur,
                                               int* __restrict__ bucket,
                                               float* __restrict__ aggr) {
    int e = blockIdx.x * 256 + threadIdx.x;
    if (e >= NE) return;
    int dst = edge[e];
    int src = edge[NE + e];
    int pos = atomicAdd(&cur[dst], 1);
    if (pos < CAP) {
        bucket[dst * CAP + pos] = src;
    } else {   // P(deg>48 | Poisson(10)) ~ 1e-17/node — correctness valve only
        const float* xr = x + (size_t)src * HD;
        float* ar = aggr + (size_t)dst * HD;
        for (int c = 0; c < HD; c++) unsafeAtomicAdd(ar + c, xr[c]);
    }
}

// ===== gather-aggregate: 4 nodes/wave (quad = node), lane covers 8 features (16B loads) =====
__global__ __launch_bounds__(256) void k_aggr(const bf16* __restrict__ xb,
                                              const int* __restrict__ cur,
                                              const int* __restrict__ bucket,
                                              float* __restrict__ aggr) {
    const int gw   = (blockIdx.x * 256 + threadIdx.x) >> 6;
    const int lane = threadIdx.x & 63;
    const int quad = lane >> 4;
    const int ln   = lane & 15;
    const int node = gw * 4 + quad;
    const bool ok  = node < NN;

    float acc[8] = {0.f, 0.f, 0.f, 0.f, 0.f, 0.f, 0.f, 0.f};
    int deg = 0, n = 0;
    const int* bk = bucket;
    if (ok) {
        deg = cur[node];
        n = (deg < CAP) ? deg : CAP;
        bk = bucket + node * CAP;
        if (deg > CAP) {
            const floatx4 s0 = *(const floatx4*)(aggr + node * HD + ln * 8);
            const floatx4 s1 = *(const floatx4*)(aggr + node * HD + ln * 8 + 4);
#pragma unroll
            for (int j = 0; j < 4; j++) { acc[j] = s0[j]; acc[4 + j] = s1[j]; }
        }
    }

    int t = 0;
    for (; t + 3 < n; t += 4) {
        int s0 = bk[t], s1 = bk[t + 1], s2 = bk[t + 2], s3 = bk[t + 3];
        const uint4 v0 = *(const uint4*)(xb + s0 * HD + ln * 8);
        const uint4 v1 = *(const uint4*)(xb + s1 * HD + ln * 8);
        const uint4 v2 = *(const uint4*)(xb + s2 * HD + ln * 8);
        const uint4 v3 = *(const uint4*)(xb + s3 * HD + ln * 8);
        const unsigned int u0[4] = {v0.x, v0.y, v0.z, v0.w};
        const unsigned int u1[4] = {v1.x, v1.y, v1.z, v1.w};
        const unsigned int u2[4] = {v2.x, v2.y, v2.z, v2.w};
        const unsigned int u3[4] = {v3.x, v3.y, v3.z, v3.w};
#pragma unroll
        for (int j = 0; j < 4; j++) {
            acc[2 * j]     += u2f(u0[j] & 0xffff) + u2f(u1[j] & 0xffff)
                            + u2f(u2[j] & 0xffff) + u2f(u3[j] & 0xffff);
            acc[2 * j + 1] += u2f(u0[j] >> 16) + u2f(u1[j] >> 16)
                            + u2f(u2[j] >> 16) + u2f(u3[j] >> 16);
        }
    }
    for (; t < n; t++) {
        const uint4 v = *(const uint4*)(xb + bk[t] * HD + ln * 8);
        const unsigned int u[4] = {v.x, v.y, v.z, v.w};
#pragma unroll
        for (int j = 0; j < 4; j++) {
            acc[2 * j]     += u2f(u[j] & 0xffff);
            acc[2 * j + 1] += u2f(u[j] >> 16);
        }
    }

    if (ok) {
        floatx4 o0, o1;
#pragma unroll
        for (int j = 0; j < 4; j++) { o0[j] = acc[j]; o1[j] = acc[4 + j]; }
        *(floatx4*)(aggr + node * HD + ln * 8) = o0;
        *(floatx4*)(aggr + node * HD + ln * 8 + 4) = o1;
    }
}

// ======== fallback atomic scatter (tier-0, proven; aggr pre-zeroed by K1) ========
__global__ __launch_bounds__(256) void k_scatter(const float* __restrict__ x,
                                                 const int* __restrict__ edge,
                                                 float* __restrict__ aggr) {
    int tid = blockIdx.x * 256 + threadIdx.x;
    int e = tid >> 5;
    int c = (tid & 31) << 2;
    int dst = edge[e];
    int src = edge[NE + e];
    const floatx4 v = *(const floatx4*)(x + src * HD + c);
    float* ap = aggr + dst * HD + c;
    unsafeAtomicAdd(ap + 0, v[0]);
    unsafeAtomicAdd(ap + 1, v[1]);
    unsafeAtomicAdd(ap + 2, v[2]);
    unsafeAtomicAdd(ap + 3, v[3]);
}

// ======== fused GEMM1+GEMM2, LDS overlay, register-prefetched A-operands ========
__global__ __launch_bounds__(256) void k_gemm12(
    const float* __restrict__ aggr, const float* __restrict__ x, const bf16* __restrict__ xb,
    int use_xb,
    const bf16* __restrict__ wlb, const bf16* __restrict__ w01b, const bf16* __restrict__ owb,
    const float* __restrict__ bias1, const float* __restrict__ bias2,
    float* __restrict__ out)
{
    __shared__ bf16 sA[128 * 136];        // wl, then ow
    __shared__ bf16 sB[128 * 136];        // w01, then tp (h transpose)
    __shared__ float b1_s[128], b2_s[128];
    float* tp = (float*)sB;               // [4][16][132]
    const int tid = threadIdx.x;

    const int lane = tid & 63;
    const int wv   = tid >> 6;
    const int ln   = lane & 15;
    const int quad = lane >> 4;
    const int row0 = blockIdx.x * 64 + wv * 16;
    const int arow = row0 + ln;
    const bool aok = arow < NN;

    // ---- prefetch all A-operand globals (12 outstanding loads/lane) ----
    floatx4 fa[8];
    bf16x8  ax[4];
    if (aok) {
#pragma unroll
        for (int kc = 0; kc < 4; kc++) {
            const int k0 = kc * 32 + quad * 8;
            fa[2 * kc]     = *(const floatx4*)(aggr + arow * 128 + k0);
            fa[2 * kc + 1] = *(const floatx4*)(aggr + arow * 128 + k0 + 4);
            if (use_xb) {
                ax[kc] = *(const bf16x8*)(xb + arow * 128 + k0);
            } else {
                const floatx4 g0 = *(const floatx4*)(x + arow * 128 + k0);
                const floatx4 g1 = *(const floatx4*)(x + arow * 128 + k0 + 4);
                ax[kc] = cvt8(g0, g1);
            }
        }
    } else {
#pragma unroll
        for (int kc = 0; kc < 4; kc++) {
            floatx4 z = {0.f, 0.f, 0.f, 0.f};
            fa[2 * kc] = z; fa[2 * kc + 1] = z; ax[kc] = zero8();
        }
    }

#pragma unroll
    for (int it = 0; it < 8; it++) {
        int i = tid + it * 256;
        int r = i >> 4;
        int o = (i & 15) << 3;
        *(bf16x8*)(sA + r * 136 + o) = *(const bf16x8*)(wlb  + r * 128 + o);
        *(bf16x8*)(sB + r * 136 + o) = *(const bf16x8*)(w01b + r * 128 + o);
    }
    if (tid < 128) { b1_s[tid] = bias1[tid]; b2_s[tid] = bias2[tid]; }
    __syncthreads();

    floatx4 acc[8] = {};

    // ---- GEMM1 ----
#pragma unroll
    for (int kc = 0; kc < 4; kc++) {
        const int k0 = kc * 32 + quad * 8;
        bf16x8 a_hi, a_lo;
        split8(fa[2 * kc], fa[2 * kc + 1], a_hi, a_lo);
#pragma unroll
        for (int nc = 0; nc < 8; nc++) {
            const bf16x8 bw  = *(const bf16x8*)(sA + (nc * 16 + ln) * 136 + k0);
            const bf16x8 bw2 = *(const bf16x8*)(sB + (nc * 16 + ln) * 136 + k0);
            acc[nc] = __builtin_amdgcn_mfma_f32_16x16x32_bf16(a_hi,  bw,  acc[nc], 0, 0, 0);
            acc[nc] = __builtin_amdgcn_mfma_f32_16x16x32_bf16(a_lo,  bw,  acc[nc], 0, 0, 0);
            acc[nc] = __builtin_amdgcn_mfma_f32_16x16x32_bf16(ax[kc], bw2, acc[nc], 0, 0, 0);
        }
    }
    __syncthreads();

    // ---- overlay: restage ow into sA; park relu(h) into tp (over sB) ----
#pragma unroll
    for (int it = 0; it < 8; it++) {
        int i = tid + it * 256;
        int r = i >> 4;
        int o = (i & 15) << 3;
        *(bf16x8*)(sA + r * 136 + o) = *(const bf16x8*)(owb + r * 128 + o);
    }
#pragma unroll
    for (int nc = 0; nc < 8; nc++) {
        const int col = nc * 16 + ln;
        const float bv = b1_s[col];
#pragma unroll
        for (int r = 0; r < 4; r++) {
            float v = acc[nc][r] + bv;
            tp[wv * 2112 + (quad * 4 + r) * 132 + col] = (v > 0.f ? v : 0.f);
        }
        acc[nc][0] = acc[nc][1] = acc[nc][2] = acc[nc][3] = 0.f;
    }
    __syncthreads();

    // ---- GEMM2 ----
#pragma unroll
    for (int kc = 0; kc < 4; kc++) {
        const int k0 = kc * 32 + quad * 8;
        const floatx4 f0 = *(const floatx4*)(tp + wv * 2112 + ln * 132 + k0);
        const floatx4 f1 = *(const floatx4*)(tp + wv * 2112 + ln * 132 + k0 + 4);
        bf16x8 a_hi, a_lo;
        split8(f0, f1, a_hi, a_lo);
#pragma unroll
        for (int nc = 0; nc < 8; nc++) {
            const bf16x8 bw = *(const bf16x8*)(sA + (nc * 16 + ln) * 136 + k0);
            acc[nc] = __builtin_amdgcn_mfma_f32_16x16x32_bf16(a_hi, bw, acc[nc], 0, 0, 0);
            acc[nc] = __builtin_amdgcn_mfma_f32_16x16x32_bf16(a_lo, bw, acc[nc], 0, 0, 0);
        }
    }

#pragma unroll
    for (int nc = 0; nc < 8; nc++) {
        const int col = nc * 16 + ln;
        const float bv = b2_s[col];
#pragma unroll
        for (int r = 0; r < 4; r++) {
            const int row = row0 + quad * 4 + r;
            if (row < NN) out[row * 128 + col] = acc[nc][r] + bv;
        }
    }
}

extern "C" void kernel_launch(void* const* d_in, const int* in_sizes, int n_in,
                              void* d_out, int out_size, void* d_ws, size_t ws_size,
                              hipStream_t stream) {
    const float* x_a     = (const float*)d_in[0];
    const int*   edge_ba = (const int*)d_in[3];
    const float* c1_w0_w = (const float*)d_in[10];
    const float* c1_w0_b = (const float*)d_in[11];
    const float* c1_wl_w = (const float*)d_in[12];
    const float* c1_wl_b = (const float*)d_in[13];
    const float* c1_w1_w = (const float*)d_in[14];
    const float* c1_w1_b = (const float*)d_in[15];
    const float* out_w   = (const float*)d_in[16];
    const float* out_b   = (const float*)d_in[17];

    char* p = (char*)d_ws;
    float* aggr  = (float*)p;   p += (size_t)NN * HD * 4;     // 25.6 MB
    bf16*  wlb   = (bf16*)p;    p += 32768;
    bf16*  w01b  = (bf16*)p;    p += 32768;
    bf16*  owb   = (bf16*)p;    p += 32768;
    float* bias1 = (float*)p;   p += 512;
    float* bias2 = (float*)p;   p += 512;
    const size_t WS_FALL = (size_t)(p - (char*)d_ws);         // ~25.7 MB
    int*   cur    = (int*)p;    p += 200704;                  // NN ints (padded)
    int*   bucket = (int*)p;    p += (size_t)NN * CAP * 4;    // 9.6 MB
    bf16*  xb     = (bf16*)p;   p += (size_t)NN * HD * 2;     // 12.8 MB
    const size_t WS_BUCKET = (size_t)(p - (char*)d_ws);       // ~48.4 MB (ws = 256 MiB)

    const int tier = (ws_size >= WS_BUCKET) ? 1 : 0;

    k_setup1<<<K1_B, 256, 0, stream>>>(c1_wl_w, c1_w0_w, c1_w1_w,
                                       c1_wl_b, c1_w0_b, c1_w1_b,
                                       out_w, out_b, x_a,
                                       wlb, w01b, owb, bias1, bias2,
                                       aggr, cur, xb, tier);

    if (tier) {
        k_fillb<<<FILLB_B, 256, 0, stream>>>(edge_ba, x_a, cur, bucket, aggr);
        k_aggr <<<3125, 256, 0, stream>>>(xb, cur, bucket, aggr);
    } else {
        k_scatter<<<NE * 32 / 256, 256, 0, stream>>>(x_a, edge_ba, aggr);
    }

    k_gemm12<<<(NN + 63) / 64, 256, 0, stream>>>(aggr, x_a, xb, tier,
                                                 wlb, w01b, owb, bias1, bias2,
                                                 (float*)d_out);
}